// Round 7
// baseline (307.808 us; speedup 1.0000x reference)
//
#include <hip/hip_runtime.h>
#include <hip/hip_cooperative_groups.h>

namespace cg = cooperative_groups;

#define NUM_CLASSES 32000
#define EMBED 128
#define NTOK (64 * 4096)
#define CLS_PER_BLK 64
#define NCHUNK (NUM_CLASSES / CLS_PER_BLK)  // 500 chunks of 64 classes
#define NREP 16                             // counter replicas per chunk
#define SUBCAP 96                           // tokens per (chunk,replica); mean 32.8
#define LDS_STRIDE 132                      // 128 + 4 floats; 16B-aligned rows
#define FUSED_THREADS 512

typedef float f32x4 __attribute__((ext_vector_type(4)));

// ---------------------------------------------------------------------------
// R7: single cooperative kernel. R6 lesson: gather scatter is write-BW bound
// (TLP doubling = zero delta), so the attackable slack is launch/memset/
// serial-staging overhead (~12-16us). Fuse:
//   Phase 0: stage W tile+bias into LDS (parallel chip-wide, was serial
//            prologue) + zero cnt slice (replaces memset launch).
//   Phase 1: bucket (replicated line-spread counters, R2 lesson).
//   Phase 2: prefix + compact to LDS + scatter (R3/R5 lessons).
// grid.sync() provides agent-scope release/acquire (cross-XCD handoff).
// ---------------------------------------------------------------------------
__global__ __launch_bounds__(FUSED_THREADS) void fused_all_kernel(
    const int* __restrict__ x, const float* __restrict__ W,
    const float* __restrict__ bias, int* __restrict__ cnt,
    int* __restrict__ ids, f32x4* __restrict__ out) {
  __shared__ float lds[CLS_PER_BLK * LDS_STRIDE];  // 33.8 KB
  __shared__ int s_ids[NREP * SUBCAP];             // 6 KB
  __shared__ int s_cnt[NREP];
  __shared__ int s_ofs[NREP + 1];

  const int chunk = blockIdx.x;  // 0..499
  const int c0 = chunk << 6;
  const int tid = threadIdx.x;
  cg::grid_group grid = cg::this_grid();

  // ---- Phase 0: stage W[:, c0:c0+64]+b into LDS; zero my cnt slice ----
  {
    const int tx4 = tid & 15;
    const int ty = tid >> 4;  // 0..31
#pragma unroll
    for (int e = ty; e < EMBED; e += 32) {
      const f32x4 w = *reinterpret_cast<const f32x4*>(
          W + (size_t)e * NUM_CLASSES + c0 + 4 * tx4);
      const float bv = bias[e];
      lds[(4 * tx4 + 0) * LDS_STRIDE + e] = w.x + bv;
      lds[(4 * tx4 + 1) * LDS_STRIDE + e] = w.y + bv;
      lds[(4 * tx4 + 2) * LDS_STRIDE + e] = w.z + bv;
      lds[(4 * tx4 + 3) * LDS_STRIDE + e] = w.w + bv;
    }
    // Zero this chunk's 16 replica counters (line-spread: 256 ints).
    for (int i = tid; i < NREP * 16; i += FUSED_THREADS)
      __hip_atomic_store(&cnt[chunk * NREP * 16 + i], 0, __ATOMIC_RELAXED,
                         __HIP_MEMORY_SCOPE_AGENT);
  }
  grid.sync();

  // ---- Phase 1: bucket all tokens (grid-stride) ----
  {
    const int gsize = NCHUNK * FUSED_THREADS;  // 256000
    const int rep = blockIdx.x & (NREP - 1);
    for (int t = blockIdx.x * FUSED_THREADS + tid; t < NTOK; t += gsize) {
      const int c = x[t];
      const int idx = (c >> 6) * NREP + rep;
      const int pos = atomicAdd(&cnt[idx * 16], 1);
      if (pos < SUBCAP) {
        ids[idx * SUBCAP + pos] = ((c & 63) << 18) | t;
      } else {
        // ~1e-24 overflow path: exact direct write, never drops.
        for (int e = 0; e < EMBED; ++e)
          out[((size_t)t * EMBED + e) >> 2][e & 3] =
              W[(size_t)e * NUM_CLASSES + c] + bias[e];
      }
    }
  }
  grid.sync();

  // ---- Phase 2: counts -> prefix -> compact -> scatter ----
  if (tid < NREP) s_cnt[tid] = min(cnt[(chunk * NREP + tid) * 16], SUBCAP);
  __syncthreads();
  if (tid == 0) {
    int acc = 0;
    for (int r = 0; r < NREP; ++r) {
      s_ofs[r] = acc;
      acc += s_cnt[r];
    }
    s_ofs[NREP] = acc;
  }
  __syncthreads();
  {
    const int r = tid >> 5;  // 0..15
    const int lane = tid & 31;
    const int nr = s_cnt[r];
    const int o = s_ofs[r];
    const int gbase = (chunk * NREP + r) * SUBCAP;
    for (int i = lane; i < nr; i += 32) s_ids[o + i] = ids[gbase + i];
  }
  __syncthreads();

  // Scatter: 16 tokens in flight, 32 lanes x 16B = 512B row per token,
  // 2-deep pipeline (ds_read of k+1 before store of k).
  const int nTot = s_ofs[NREP];
  const int slot = tid >> 5;  // 0..15
  const int j = tid & 31;
  int i = slot;
  if (i < nTot) {
    int pk = s_ids[i];
    f32x4 v =
        *reinterpret_cast<const f32x4*>(&lds[(pk >> 18) * LDS_STRIDE + 4 * j]);
    int t = pk & 0x3FFFF;
    for (i += 16; i < nTot; i += 16) {
      const int pk1 = s_ids[i];
      const f32x4 v1 = *reinterpret_cast<const f32x4*>(
          &lds[(pk1 >> 18) * LDS_STRIDE + 4 * j]);
      __builtin_nontemporal_store(v, &out[(size_t)t * 32 + j]);
      v = v1;
      t = pk1 & 0x3FFFF;
    }
    __builtin_nontemporal_store(v, &out[(size_t)t * 32 + j]);
  }
}

// ---------------------------------------------------------------------------
// Fallback A: proven 3-kernel path (R6, 174.8us) if coop launch fails.
// ---------------------------------------------------------------------------
__global__ __launch_bounds__(256) void bucket_kernel(
    const int* __restrict__ x, int* __restrict__ cnt, int* __restrict__ ids,
    const float* __restrict__ W, const float* __restrict__ bias,
    float* __restrict__ out) {
  const int t = blockIdx.x * 256 + threadIdx.x;
  const int c = x[t];
  const int idx = (c >> 6) * NREP + (blockIdx.x & (NREP - 1));
  const int pos = atomicAdd(&cnt[idx * 16], 1);
  if (pos < SUBCAP) {
    ids[idx * SUBCAP + pos] = ((c & 63) << 18) | t;
  } else {
    for (int e = 0; e < EMBED; ++e)
      out[(size_t)t * EMBED + e] = W[(size_t)e * NUM_CLASSES + c] + bias[e];
  }
}

__global__ __launch_bounds__(512) void fused_gather_kernel(
    const float* __restrict__ W, const float* __restrict__ bias,
    const int* __restrict__ cnt, const int* __restrict__ ids,
    f32x4* __restrict__ out) {
  __shared__ float lds[CLS_PER_BLK * LDS_STRIDE];
  __shared__ int s_ids[NREP * SUBCAP];
  __shared__ int s_cnt[NREP];
  __shared__ int s_ofs[NREP + 1];
  const int chunk = blockIdx.x;
  const int c0 = chunk << 6;
  const int tid = threadIdx.x;
  if (tid < NREP) s_cnt[tid] = min(cnt[(chunk * NREP + tid) * 16], SUBCAP);
  const int tx4 = tid & 15;
  const int ty = tid >> 4;
#pragma unroll
  for (int e = ty; e < EMBED; e += 32) {
    const f32x4 w = *reinterpret_cast<const f32x4*>(
        W + (size_t)e * NUM_CLASSES + c0 + 4 * tx4);
    const float bv = bias[e];
    lds[(4 * tx4 + 0) * LDS_STRIDE + e] = w.x + bv;
    lds[(4 * tx4 + 1) * LDS_STRIDE + e] = w.y + bv;
    lds[(4 * tx4 + 2) * LDS_STRIDE + e] = w.z + bv;
    lds[(4 * tx4 + 3) * LDS_STRIDE + e] = w.w + bv;
  }
  __syncthreads();
  if (tid == 0) {
    int acc = 0;
    for (int r = 0; r < NREP; ++r) {
      s_ofs[r] = acc;
      acc += s_cnt[r];
    }
    s_ofs[NREP] = acc;
  }
  __syncthreads();
  {
    const int r = tid >> 5;
    const int lane = tid & 31;
    const int nr = s_cnt[r];
    const int o = s_ofs[r];
    const int gbase = (chunk * NREP + r) * SUBCAP;
    for (int i = lane; i < nr; i += 32) s_ids[o + i] = ids[gbase + i];
  }
  __syncthreads();
  const int nTot = s_ofs[NREP];
  const int slot = tid >> 5;
  const int j = tid & 31;
  int i = slot;
  if (i < nTot) {
    int pk = s_ids[i];
    f32x4 v =
        *reinterpret_cast<const f32x4*>(&lds[(pk >> 18) * LDS_STRIDE + 4 * j]);
    int t = pk & 0x3FFFF;
    for (i += 16; i < nTot; i += 16) {
      const int pk1 = s_ids[i];
      const f32x4 v1 = *reinterpret_cast<const f32x4*>(
          &lds[(pk1 >> 18) * LDS_STRIDE + 4 * j]);
      __builtin_nontemporal_store(v, &out[(size_t)t * 32 + j]);
      v = v1;
      t = pk1 & 0x3FFFF;
    }
    __builtin_nontemporal_store(v, &out[(size_t)t * 32 + j]);
  }
}

// ---------------------------------------------------------------------------
// Fallback B: no usable workspace at all.
// ---------------------------------------------------------------------------
__global__ __launch_bounds__(256) void direct_kernel(
    const int* __restrict__ x, const float* __restrict__ W,
    const float* __restrict__ bias, float* __restrict__ out) {
  const int g = blockIdx.x * 256 + threadIdx.x;
  const int token = g >> 7;
  const int e = g & 127;
  const int c = x[token];
  out[g] = W[(size_t)e * NUM_CLASSES + c] + bias[e];
}

extern "C" void kernel_launch(void* const* d_in, const int* in_sizes, int n_in,
                              void* d_out, int out_size, void* d_ws,
                              size_t ws_size, hipStream_t stream) {
  const int* x = (const int*)d_in[0];
  const float* W = (const float*)d_in[1];
  const float* bias = (const float*)d_in[2];
  float* out = (float*)d_out;

  const size_t cnt_bytes = (size_t)NCHUNK * NREP * 16 * sizeof(int);  // 512 KB
  const size_t ids_bytes = (size_t)NCHUNK * NREP * SUBCAP * sizeof(int);
  const size_t need_bucket = cnt_bytes + ids_bytes;  // ~3.6 MB

  if (ws_size >= need_bucket) {
    int* cnt = (int*)d_ws;
    int* ids = (int*)((char*)d_ws + cnt_bytes);
    f32x4* out4 = (f32x4*)out;

    const int* x_ = x;
    const float* W_ = W;
    const float* b_ = bias;
    int* cnt_ = cnt;
    int* ids_ = ids;
    f32x4* out_ = out4;
    void* args[] = {&x_, &W_, &b_, &cnt_, &ids_, &out_};
    hipError_t err = hipLaunchCooperativeKernel(
        (const void*)fused_all_kernel, dim3(NCHUNK), dim3(FUSED_THREADS), args,
        0, stream);
    if (err == hipSuccess) return;

    // Cooperative launch unavailable: proven 3-kernel path.
    (void)hipMemsetAsync(cnt, 0, cnt_bytes, stream);
    bucket_kernel<<<NTOK / 256, 256, 0, stream>>>(x, cnt, ids, W, bias, out);
    fused_gather_kernel<<<NCHUNK, 512, 0, stream>>>(W, bias, cnt, ids, out4);
  } else {
    direct_kernel<<<(NTOK * EMBED) / 256, 256, 0, stream>>>(x, W, bias, out);
  }
}

// Round 8
// 166.443 us; speedup vs baseline: 1.8493x; 1.8493x over previous
//
#include <hip/hip_runtime.h>

#define NUM_CLASSES 32000
#define EMBED 128
#define NTOK (64 * 4096)
#define CLS_PER_BLK 64
#define NCHUNK (NUM_CLASSES / CLS_PER_BLK)  // 500 chunks of 64 classes
#define NREP 16                             // counter replicas per chunk
#define SUBCAP 96                           // tokens per (chunk,replica); mean 32.8
#define LDS_STRIDE 132                      // 128 + 4 floats; 16B-aligned rows

typedef float f32x4 __attribute__((ext_vector_type(4)));
typedef int i32x4 __attribute__((ext_vector_type(4)));

// ---------------------------------------------------------------------------
// Kernel A: bucket tokens by 64-class chunk. 16-way replicated counters, one
// counter per 64B line (R2 lesson: packed counters = 84us same-line atomic
// serialization). 4 tokens/thread via int4 = 4 independent atomic chains.
// Entry packs (c_local << 18) | token  (token < 2^18 = 262144 exactly).
// ---------------------------------------------------------------------------
__global__ __launch_bounds__(256) void bucket_kernel(
    const int* __restrict__ x, int* __restrict__ cnt, int* __restrict__ ids,
    const float* __restrict__ W, const float* __restrict__ bias,
    float* __restrict__ out) {
  const int g = blockIdx.x * 256 + threadIdx.x;
  const i32x4 cv = reinterpret_cast<const i32x4*>(x)[g];
  const int rep = blockIdx.x & (NREP - 1);
  const int t0 = g * 4;
#pragma unroll
  for (int k = 0; k < 4; ++k) {
    const int c = cv[k];
    const int t = t0 + k;
    const int idx = (c >> 6) * NREP + rep;
    const int pos = atomicAdd(&cnt[idx * 16], 1);  // *16: one counter per line
    if (pos < SUBCAP) {
      ids[idx * SUBCAP + pos] = ((c & 63) << 18) | t;
    } else {
      // ~1e-24 probability overflow path: exact direct write, never drops.
      for (int e = 0; e < EMBED; ++e)
        out[(size_t)t * EMBED + e] = W[(size_t)e * NUM_CLASSES + c] + bias[e];
    }
  }
}

// ---------------------------------------------------------------------------
// Kernel B: fused transpose+bias (LDS tile, one block per 64-class chunk)
// + dedup'd scatter. R7 lesson (direct counters): kernel is PURE WRITE-STALL
// (VALUBusy 1.6%, FETCH 9.7MB, WRITE 145MB). R8 A/B: plain stores instead of
// nontemporal — let L2 write-allocate + TCC writeback batch the scattered
// 512B granules (the 6.3TB/s fill path) instead of nt's direct-to-HBM
// fine-grained bursts.
// ---------------------------------------------------------------------------
__global__ __launch_bounds__(1024) void fused_gather_kernel(
    const float* __restrict__ W, const float* __restrict__ bias,
    const int* __restrict__ cnt, const int* __restrict__ ids,
    f32x4* __restrict__ out) {
  __shared__ float lds[CLS_PER_BLK * LDS_STRIDE];  // 33.8 KB
  __shared__ int s_ids[NREP * SUBCAP];             // 6 KB dense token list
  __shared__ int s_cnt[NREP];
  __shared__ int s_ofs[NREP + 1];

  const int chunk = blockIdx.x;
  const int c0 = chunk << 6;
  const int tid = threadIdx.x;

  // Replica counts (16 parallel loads).
  if (tid < NREP) s_cnt[tid] = min(cnt[(chunk * NREP + tid) * 16], SUBCAP);

  // Stage phase: thread (tx4,ty) reads 4 classes of embed-row e, transposes.
  const int tx4 = tid & 15;
  const int ty = tid >> 4;  // 0..63
#pragma unroll
  for (int e = ty; e < EMBED; e += 64) {
    const f32x4 w = *reinterpret_cast<const f32x4*>(
        W + (size_t)e * NUM_CLASSES + c0 + 4 * tx4);
    const float bv = bias[e];
    lds[(4 * tx4 + 0) * LDS_STRIDE + e] = w.x + bv;
    lds[(4 * tx4 + 1) * LDS_STRIDE + e] = w.y + bv;
    lds[(4 * tx4 + 2) * LDS_STRIDE + e] = w.z + bv;
    lds[(4 * tx4 + 3) * LDS_STRIDE + e] = w.w + bv;
  }
  __syncthreads();

  // Tiny serial prefix over 16 counts.
  if (tid == 0) {
    int acc = 0;
    for (int r = 0; r < NREP; ++r) {
      s_ofs[r] = acc;
      acc += s_cnt[r];
    }
    s_ofs[NREP] = acc;
  }
  __syncthreads();

  // Compact the 16 sub-lists into one dense LDS list: one 64-lane wave per
  // replica (<=96 entries -> 2 coalesced iterations).
  {
    const int r = tid >> 6;  // 0..15
    const int lane = tid & 63;
    const int nr = s_cnt[r];
    const int o = s_ofs[r];
    const int gbase = (chunk * NREP + r) * SUBCAP;
    for (int i = lane; i < nr; i += 64) s_ids[o + i] = ids[gbase + i];
  }
  __syncthreads();

  // Scatter phase: 32 tokens in flight, 32 lanes x 16B = 512B row per token.
  // 2-deep pipeline: row ds_read of token k+1 issued before store of token k.
  const int nTot = s_ofs[NREP];
  const int slot = tid >> 5;  // 0..31
  const int j = tid & 31;     // f32x4 index within the 128-f32 row
  int i = slot;
  if (i < nTot) {
    int pk = s_ids[i];
    f32x4 v = *reinterpret_cast<const f32x4*>(
        &lds[(pk >> 18) * LDS_STRIDE + 4 * j]);
    int t = pk & 0x3FFFF;
    for (i += 32; i < nTot; i += 32) {
      const int pk1 = s_ids[i];
      const f32x4 v1 = *reinterpret_cast<const f32x4*>(
          &lds[(pk1 >> 18) * LDS_STRIDE + 4 * j]);
      out[(size_t)t * 32 + j] = v;  // plain store: L2 write-allocate path
      v = v1;
      t = pk1 & 0x3FFFF;
    }
    out[(size_t)t * 32 + j] = v;
  }
}

// ---------------------------------------------------------------------------
// Fallback 1: table in ws + gather (the 177us baseline path).
// ---------------------------------------------------------------------------
__global__ __launch_bounds__(256) void build_table_kernel(
    const float* __restrict__ W, const float* __restrict__ bias,
    float* __restrict__ Wb) {
  __shared__ float lds[EMBED * (CLS_PER_BLK + 1)];
  const int c0 = blockIdx.x * CLS_PER_BLK;
  const int tid = threadIdx.x;
  const int tx = tid & 63;
  const int ty = tid >> 6;
  for (int e = ty; e < EMBED; e += 4) {
    lds[e * (CLS_PER_BLK + 1) + tx] = W[(size_t)e * NUM_CLASSES + c0 + tx];
  }
  __syncthreads();
  const int e = tid & 127;
  const int half = tid >> 7;
  const float bv = bias[e];
  for (int ci = half; ci < CLS_PER_BLK; ci += 2) {
    Wb[(size_t)(c0 + ci) * EMBED + e] = lds[e * (CLS_PER_BLK + 1) + ci] + bv;
  }
}

__global__ __launch_bounds__(256) void gather_kernel(
    const int* __restrict__ x, const float* __restrict__ Wb,
    float* __restrict__ out) {
  const int g = blockIdx.x * 256 + threadIdx.x;
  const int token = g >> 5;
  const int j = g & 31;
  const int c = x[token];
  reinterpret_cast<f32x4*>(out)[g] =
      reinterpret_cast<const f32x4*>(Wb)[(size_t)c * 32 + j];
}

// ---------------------------------------------------------------------------
// Fallback 2: no usable workspace at all.
// ---------------------------------------------------------------------------
__global__ __launch_bounds__(256) void direct_kernel(
    const int* __restrict__ x, const float* __restrict__ W,
    const float* __restrict__ bias, float* __restrict__ out) {
  const int g = blockIdx.x * 256 + threadIdx.x;
  const int token = g >> 7;
  const int e = g & 127;
  const int c = x[token];
  out[g] = W[(size_t)e * NUM_CLASSES + c] + bias[e];
}

extern "C" void kernel_launch(void* const* d_in, const int* in_sizes, int n_in,
                              void* d_out, int out_size, void* d_ws,
                              size_t ws_size, hipStream_t stream) {
  const int* x = (const int*)d_in[0];
  const float* W = (const float*)d_in[1];
  const float* bias = (const float*)d_in[2];
  float* out = (float*)d_out;

  const size_t cnt_bytes = (size_t)NCHUNK * NREP * 16 * sizeof(int);  // 512 KB
  const size_t ids_bytes = (size_t)NCHUNK * NREP * SUBCAP * sizeof(int);
  const size_t need_bucket = cnt_bytes + ids_bytes;  // ~3.6 MB
  const size_t table_bytes = (size_t)NUM_CLASSES * EMBED * sizeof(float);

  if (ws_size >= need_bucket) {
    int* cnt = (int*)d_ws;
    int* ids = (int*)((char*)d_ws + cnt_bytes);
    (void)hipMemsetAsync(cnt, 0, cnt_bytes, stream);
    bucket_kernel<<<NTOK / 1024, 256, 0, stream>>>(x, cnt, ids, W, bias, out);
    fused_gather_kernel<<<NCHUNK, 1024, 0, stream>>>(W, bias, cnt, ids,
                                                     (f32x4*)out);
  } else if (ws_size >= table_bytes) {
    float* Wb = (float*)d_ws;
    build_table_kernel<<<NUM_CLASSES / CLS_PER_BLK, 256, 0, stream>>>(W, bias,
                                                                      Wb);
    gather_kernel<<<(NTOK * 32) / 256, 256, 0, stream>>>(x, Wb, out);
  } else {
    direct_kernel<<<(NTOK * EMBED) / 256, 256, 0, stream>>>(x, W, bias, out);
  }
}